// Round 17
// baseline (84.864 us; speedup 1.0000x reference)
//
#include <hip/hip_runtime.h>
#include <hip/hip_bf16.h>

// ODELSTMCell: B=16384, I=256, H=256, OH=64, 8 fixed dopri5 steps.
// prep_kernel : wsB=[W_ih|W_hh] bf16; Wc=W1@W2 bf16; u=b2@W1^T f32;
//               w1B=W1 bf16; w2B=W2 bf16.
// lstm_kernel : R16-verified m97-shaped GEMM + T14 async-stage split (~35us).
// ode_kernel  : R13-exact zc-space zero-exchange dopri5 + two micro-opts:
//               (1) scaled-exp2 tanh domain (G2 = K2*(G+b1), dt2 = K2*dt)
//               (2) split-accumulator wcmm (2 independent MFMAs + add).

#define B_N 16384
#define H_N 256

typedef __attribute__((ext_vector_type(8))) short short8;          // 8 x bf16
typedef __attribute__((ext_vector_type(4))) unsigned short u16x4;  // 4 x bf16
typedef __attribute__((ext_vector_type(4))) float f32x4;

__device__ __forceinline__ unsigned short f2bf_s(float x) {
  __hip_bfloat16 h = __float2bfloat16(x);
  return *reinterpret_cast<unsigned short*>(&h);
}

__device__ __forceinline__ short8 pack8f(const float* p) {
  const f32x4 a = *(const f32x4*)p;
  const f32x4 b = *(const f32x4*)(p + 4);
  short8 r;
  r[0] = (short)f2bf_s(a[0]); r[1] = (short)f2bf_s(a[1]);
  r[2] = (short)f2bf_s(a[2]); r[3] = (short)f2bf_s(a[3]);
  r[4] = (short)f2bf_s(b[0]); r[5] = (short)f2bf_s(b[1]);
  r[6] = (short)f2bf_s(b[2]); r[7] = (short)f2bf_s(b[3]);
  return r;
}

__device__ __forceinline__ short8 pack8v(f32x4 a, f32x4 b) {
  short8 r;
  r[0] = (short)f2bf_s(a[0]); r[1] = (short)f2bf_s(a[1]);
  r[2] = (short)f2bf_s(a[2]); r[3] = (short)f2bf_s(a[3]);
  r[4] = (short)f2bf_s(b[0]); r[5] = (short)f2bf_s(b[1]);
  r[6] = (short)f2bf_s(b[2]); r[7] = (short)f2bf_s(b[3]);
  return r;
}

__device__ __forceinline__ float fast_sigmoid(float x) {
  return __builtin_amdgcn_rcpf(1.f + __expf(-x));
}
// clamp-free: e^inf -> rcp 0 -> 1; e^-inf -> 0 -> -1  (exact limits)
__device__ __forceinline__ float fast_tanh(float x) {
  float e = __expf(2.f * x);
  return 1.f - 2.f * __builtin_amdgcn_rcpf(e + 1.f);
}
// scaled domain: a2 = 2*log2(e)*x ; tanh(x) = 1 - 2/(exp2(a2)+1)
__device__ __forceinline__ float tanh_s(float a2) {
  float e = exp2f(a2);
  return 1.f - 2.f * __builtin_amdgcn_rcpf(e + 1.f);
}

__device__ __forceinline__ void gl_lds16(const void* g, void* l) {
  __builtin_amdgcn_global_load_lds(
      (const __attribute__((address_space(1))) void*)g,
      (__attribute__((address_space(3))) void*)l, 16, 0, 0);
}

// ---------------------------------------------------------------------------
// prep: [0,256) wsB; [256,272) Wc=W1@W2; 272 u=b2@W1^T; [273,281) w1B; [281,289) w2B
// ---------------------------------------------------------------------------
__global__ __launch_bounds__(256) void prep_kernel(
    const float* __restrict__ Wih, const float* __restrict__ Whh,
    const float* __restrict__ W1, const float* __restrict__ W2,
    const float* __restrict__ b2,
    unsigned short* __restrict__ wsB, unsigned short* __restrict__ wcB,
    float* __restrict__ uF, unsigned short* __restrict__ w1B,
    unsigned short* __restrict__ w2B) {
  const int bx = blockIdx.x;
  if (bx < 256) {
    int idx = bx * 256 + threadIdx.x;
    int n = idx >> 6, c = idx & 63, k = c * 8;
    const float* src = (k < 256) ? (Wih + (size_t)n * 256 + k)
                                 : (Whh + (size_t)n * 256 + (k - 256));
    *(short8*)(wsB + (size_t)n * 512 + k) = pack8f(src);
  } else if (bx < 272) {
    int idx = (bx - 256) * 256 + threadIdx.x;  // [0,4096)
    int f = idx >> 6, o = idx & 63;
    float a0 = 0.f, a1 = 0.f, a2 = 0.f, a3 = 0.f;
    for (int h = 0; h < 256; h += 4) {
      a0 = fmaf(W1[f * 256 + h],     W2[h * 64 + o],        a0);
      a1 = fmaf(W1[f * 256 + h + 1], W2[(h + 1) * 64 + o],  a1);
      a2 = fmaf(W1[f * 256 + h + 2], W2[(h + 2) * 64 + o],  a2);
      a3 = fmaf(W1[f * 256 + h + 3], W2[(h + 3) * 64 + o],  a3);
    }
    wcB[f * 64 + o] = f2bf_s((a0 + a1) + (a2 + a3));
  } else if (bx == 272) {
    int f = threadIdx.x;
    if (f < 64) {
      float a0 = 0.f, a1 = 0.f, a2 = 0.f, a3 = 0.f;
      for (int h = 0; h < 256; h += 4) {
        a0 = fmaf(W1[f * 256 + h],     b2[h],     a0);
        a1 = fmaf(W1[f * 256 + h + 1], b2[h + 1], a1);
        a2 = fmaf(W1[f * 256 + h + 2], b2[h + 2], a2);
        a3 = fmaf(W1[f * 256 + h + 3], b2[h + 3], a3);
      }
      uF[f] = (a0 + a1) + (a2 + a3);
    }
  } else if (bx < 281) {
    int idx = (bx - 273) * 256 + threadIdx.x;  // [0,2048)
    *(short8*)(w1B + (size_t)idx * 8) = pack8f(W1 + (size_t)idx * 8);
  } else {
    int idx = (bx - 281) * 256 + threadIdx.x;  // [0,2048)
    *(short8*)(w2B + (size_t)idx * 8) = pack8f(W2 + (size_t)idx * 8);
  }
}

// ---------------------------------------------------------------------------
// lstm (R16-verified, unchanged): grid (128, 4), 512 thr.
// Iter kt: ALOAD(kt+1) early -> compute(kt) -> barrier -> AWRITE + BSTAGE ->
// barrier. A HBM latency hides under MFMA compute.
// ---------------------------------------------------------------------------
__global__ __launch_bounds__(512, 4) void lstm_kernel(
    const float* __restrict__ x, const float* __restrict__ hp,
    const float* __restrict__ cp, const unsigned short* __restrict__ wsB,
    const float* __restrict__ bih, const float* __restrict__ bhh,
    float* __restrict__ out) {
  __shared__ __align__(16) unsigned short Abf[2][128 * 32];  // 8KB x2
  __shared__ __align__(16) unsigned short Bbf[2][256 * 32];  // 16KB x2

  const int tid = threadIdx.x;
  const int lane = tid & 63;
  const int wv = tid >> 6;
  const int rg = wv >> 2;
  const int cg = wv & 3;
  const int s = lane & 15, q = lane >> 4;
  const int mb = blockIdx.x * 128;
  const int hb = blockIdx.y;

  f32x4 acc[4][4];
#pragma unroll
  for (int mt = 0; mt < 4; ++mt)
#pragma unroll
    for (int g = 0; g < 4; ++g) acc[mt][g] = (f32x4){0.f, 0.f, 0.f, 0.f};

  const int rA = tid >> 2, q4 = tid & 3;
  const int physA = q4 ^ ((rA >> 1) & 3);

  auto BSTAGE = [&](int kt) {
#pragma unroll
    for (int u = 0; u < 2; ++u)
#pragma unroll
      for (int j = 0; j < 2; ++j) {
        int c = wv * 32 + j * 16 + (lane >> 2);
        int lc = (lane & 3) ^ ((c >> 1) & 3);
        int n = (c >> 6) * 256 + hb * 64 + (c & 63);
        gl_lds16(wsB + (size_t)n * 512 + kt * 64 + u * 32 + lc * 8,
                 (char*)Bbf[u] + (wv * 32 + j * 16) * 64);
      }
  };

  f32x4 pa0[2], pa1[2];
  auto ALOAD = [&](int kt) {
    const float* srcA = (kt < 4) ? x : hp;
    const int kl = (kt * 64) & 255;
#pragma unroll
    for (int u = 0; u < 2; ++u) {
      const float* ap = srcA + (size_t)(mb + rA) * 256 + kl + u * 32 + q4 * 8;
      pa0[u] = *(const f32x4*)ap;
      pa1[u] = *(const f32x4*)(ap + 4);
    }
  };
  auto AWRITE = [&]() {
#pragma unroll
    for (int u = 0; u < 2; ++u)
      *(short8*)((char*)Abf[u] + rA * 64 + physA * 16) = pack8v(pa0[u], pa1[u]);
  };

  ALOAD(0);
  AWRITE();
  BSTAGE(0);
  __syncthreads();

  for (int kt = 0; kt < 8; ++kt) {
    if (kt < 7) ALOAD(kt + 1);

#pragma unroll
    for (int u = 0; u < 2; ++u) {
      short8 af[4];
#pragma unroll
      for (int mt = 0; mt < 4; ++mt) {
        int r = rg * 64 + mt * 16 + s;
        af[mt] = *(const short8*)((char*)Abf[u] + r * 64 +
                                  ((q ^ ((r >> 1) & 3)) << 4));
      }
#pragma unroll
      for (int g = 0; g < 4; ++g) {
        int c = (g * 4 + cg) * 16 + s;
        short8 bfr = *(const short8*)((char*)Bbf[u] + c * 64 +
                                      ((q ^ ((c >> 1) & 3)) << 4));
#pragma unroll
        for (int mt = 0; mt < 4; ++mt)
          acc[mt][g] =
              __builtin_amdgcn_mfma_f32_16x16x32_bf16(af[mt], bfr, acc[mt][g], 0, 0, 0);
      }
    }
    __syncthreads();

    if (kt < 7) {
      AWRITE();
      BSTAGE(kt + 1);
      __syncthreads();
    }
  }

#pragma unroll
  for (int mt = 0; mt < 4; ++mt)
#pragma unroll
    for (int r = 0; r < 4; ++r) {
      int sample = mb + rg * 64 + mt * 16 + q * 4 + r;
      int h = hb * 64 + cg * 16 + s;
      float gi = acc[mt][0][r] + bih[h] + bhh[h];
      float gf = acc[mt][1][r] + bih[256 + h] + bhh[256 + h];
      float gg = acc[mt][2][r] + bih[512 + h] + bhh[512 + h];
      float go = acc[mt][3][r] + bih[768 + h] + bhh[768 + h];
      float iv = fast_sigmoid(gi), fv = fast_sigmoid(gf);
      float gv = fast_tanh(gg), ov = fast_sigmoid(go);
      float c = fv * cp[(size_t)sample * 256 + h] + iv * gv;
      float hv = ov * fast_tanh(c);
      out[(size_t)B_N * H_N + (size_t)sample * 256 + h] = c;
      out[(size_t)sample * 256 + h] = hv;
    }
}

// ---------------------------------------------------------------------------
// ode: zc-space zero-exchange per-wave dopri5 (R13 structure) + scaled-exp2
// domain + split-accumulator wcmm. 64 thr = 1 wave = 16 samples.
// ---------------------------------------------------------------------------
__global__ __launch_bounds__(64) void ode_kernel(
    float* __restrict__ out, const float* __restrict__ ts,
    const unsigned short* __restrict__ wcB, const float* __restrict__ uF,
    const unsigned short* __restrict__ w1B, const unsigned short* __restrict__ w2B,
    const float* __restrict__ b1, const float* __restrict__ b2) {
  const int lane = threadIdx.x;
  const int s = lane & 15, q = lane >> 4;
  const int bb = blockIdx.x * 16;

  auto grow = [&](int i) {
    return (i >> 1) * 32 + ((s >> 2) * 8) + (i & 1) * 4 + (s & 3);
  };
  auto fbase = [&](int i) { return (i >> 1) * 32 + q * 8 + (i & 1) * 4; };

  short8 wcf[4][2];
#pragma unroll
  for (int i = 0; i < 4; ++i) {
    const int gr = grow(i);
#pragma unroll
    for (int kt = 0; kt < 2; ++kt)
      wcf[i][kt] = *(const short8*)(wcB + (size_t)gr * 64 + kt * 32 + q * 8);
  }
  f32x4 u4[4];
#pragma unroll
  for (int i = 0; i < 4; ++i) u4[i] = *(const f32x4*)(uF + fbase(i));

  const float K2 = 2.8853900817779268f;  // 2*log2(e)
  const float dt = ts[bb + s] * 0.125f;
  const float dt2 = dt * K2;

  // G0 = y0 @ W1^T (rows permuted); G2 = K2*(G0 + b1)  (scaled domain)
  f32x4 G2[4];
#pragma unroll
  for (int i = 0; i < 4; ++i) G2[i] = (f32x4){0.f, 0.f, 0.f, 0.f};
#pragma unroll
  for (int kt = 0; kt < 8; ++kt) {
    short8 yf = pack8f(out + (size_t)(bb + s) * 256 + kt * 32 + q * 8);
#pragma unroll
    for (int i = 0; i < 4; ++i) {
      short8 w1f =
          *(const short8*)(w1B + (size_t)grow(i) * 256 + kt * 32 + q * 8);
      G2[i] = __builtin_amdgcn_mfma_f32_16x16x32_bf16(w1f, yf, G2[i], 0, 0, 0);
    }
  }
#pragma unroll
  for (int i = 0; i < 4; ++i) {
    f32x4 b1v = *(const f32x4*)(b1 + fbase(i));
#pragma unroll
    for (int r = 0; r < 4; ++r) G2[i][r] = (G2[i][r] + b1v[r]) * K2;
  }

  // o = zc @ Wc^T (split accumulators: 2 independent MFMAs per tile)
  auto wcmm = [&](const f32x4 (&zc)[4], f32x4 (&o)[4]) {
    short8 zf0 = pack8v(zc[0], zc[1]);
    short8 zf1 = pack8v(zc[2], zc[3]);
#pragma unroll
    for (int i = 0; i < 4; ++i) {
      f32x4 zero = (f32x4){0.f, 0.f, 0.f, 0.f};
      f32x4 a0 = __builtin_amdgcn_mfma_f32_16x16x32_bf16(wcf[i][0], zf0, zero, 0, 0, 0);
      f32x4 a1 = __builtin_amdgcn_mfma_f32_16x16x32_bf16(wcf[i][1], zf1, zero, 0, 0, 0);
      o[i] = a0 + a1;
    }
  };
  // stage: z_out = tanh_s(G2 + dt2*(cj*u + o))
  auto stage = [&](const f32x4 (&zc)[4], float cj, f32x4 (&zo)[4]) {
    f32x4 o[4];
    wcmm(zc, o);
#pragma unroll
    for (int i = 0; i < 4; ++i)
#pragma unroll
      for (int r = 0; r < 4; ++r)
        zo[i][r] = tanh_s(fmaf(dt2, fmaf(cj, u4[i][r], o[i][r]), G2[i][r]));
  };

  const float A31 = 3.f / 40.f, A32 = 9.f / 40.f;
  const float A41 = 44.f / 45.f, A42 = -56.f / 15.f, A43 = 32.f / 9.f;
  const float A51 = 19372.f / 6561.f, A52 = -25360.f / 2187.f,
              A53 = 64448.f / 6561.f, A54 = -212.f / 729.f;
  const float A61 = 9017.f / 3168.f, A62 = -355.f / 33.f, A63 = 46732.f / 5247.f,
              A64 = 49.f / 176.f, A65 = -5103.f / 18656.f;
  const float C1 = 35.f / 384.f, C3 = 500.f / 1113.f, C4 = 125.f / 192.f,
              C5 = -2187.f / 6784.f, C6 = 11.f / 84.f;

  f32x4 SC[4];
#pragma unroll
  for (int i = 0; i < 4; ++i) SC[i] = (f32x4){0.f, 0.f, 0.f, 0.f};
  f32x4 z1[4], z2[4], z3[4], z4[4], z5[4], zc[4];

  for (int st = 0; st < 8; ++st) {
#pragma unroll
    for (int i = 0; i < 4; ++i)
#pragma unroll
      for (int r = 0; r < 4; ++r) z1[i][r] = tanh_s(G2[i][r]);

#pragma unroll
    for (int i = 0; i < 4; ++i) zc[i] = 0.2f * z1[i];
    stage(zc, 0.2f, z2);
#pragma unroll
    for (int i = 0; i < 4; ++i) zc[i] = A31 * z1[i] + A32 * z2[i];
    stage(zc, 0.3f, z3);
#pragma unroll
    for (int i = 0; i < 4; ++i) zc[i] = A41 * z1[i] + A42 * z2[i] + A43 * z3[i];
    stage(zc, 0.8f, z4);
#pragma unroll
    for (int i = 0; i < 4; ++i)
      zc[i] = A51 * z1[i] + A52 * z2[i] + A53 * z3[i] + A54 * z4[i];
    stage(zc, 8.f / 9.f, z5);
#pragma unroll
    for (int i = 0; i < 4; ++i)
      zc[i] = A61 * z1[i] + A62 * z2[i] + A63 * z3[i] + A64 * z4[i] + A65 * z5[i];
    // stage 6 fused: z6 transient, output-combo built in place (c6 = 1)
    {
      f32x4 o[4];
      wcmm(zc, o);
#pragma unroll
      for (int i = 0; i < 4; ++i)
#pragma unroll
        for (int r = 0; r < 4; ++r) {
          float z6v = tanh_s(fmaf(dt2, u4[i][r] + o[i][r], G2[i][r]));
          zc[i][r] = C1 * z1[i][r] + C3 * z3[i][r] + C4 * z4[i][r] +
                     C5 * z5[i][r] + C6 * z6v;
        }
    }
    // G2 += dt2*(u + zC@Wc^T); SC += zC
    {
      f32x4 o6[4];
      wcmm(zc, o6);
#pragma unroll
      for (int i = 0; i < 4; ++i) {
        SC[i] += zc[i];
#pragma unroll
        for (int r = 0; r < 4; ++r)
          G2[i][r] = fmaf(dt2, u4[i][r] + o6[i][r], G2[i][r]);
      }
    }
  }

  // epilogue: y = y0 + dt*(8*b2 + SC@W2^T)  (normal domain)
  {
    short8 sf0 = pack8v(SC[0], SC[1]);
    short8 sf1 = pack8v(SC[2], SC[3]);
#pragma unroll
    for (int ft = 0; ft < 16; ++ft) {
      short8 w2a = *(const short8*)(w2B + (size_t)(ft * 16 + s) * 64 + q * 8);
      short8 w2b = *(const short8*)(w2B + (size_t)(ft * 16 + s) * 64 + 32 + q * 8);
      f32x4 zero = (f32x4){0.f, 0.f, 0.f, 0.f};
      f32x4 a0 = __builtin_amdgcn_mfma_f32_16x16x32_bf16(w2a, sf0, zero, 0, 0, 0);
      f32x4 a1 = __builtin_amdgcn_mfma_f32_16x16x32_bf16(w2b, sf1, zero, 0, 0, 0);
      f32x4 y0 = *(const f32x4*)(out + (size_t)(bb + s) * 256 + ft * 16 + q * 4);
      f32x4 b2v = *(const f32x4*)(b2 + ft * 16 + q * 4);
#pragma unroll
      for (int r = 0; r < 4; ++r)
        y0[r] = fmaf(dt, fmaf(8.f, b2v[r], a0[r] + a1[r]), y0[r]);
      *(f32x4*)(out + (size_t)(bb + s) * 256 + ft * 16 + q * 4) = y0;
    }
  }
}

extern "C" void kernel_launch(void* const* d_in, const int* in_sizes, int n_in,
                              void* d_out, int out_size, void* d_ws, size_t ws_size,
                              hipStream_t stream) {
  const float* x   = (const float*)d_in[0];
  const float* hp  = (const float*)d_in[1];
  const float* cp  = (const float*)d_in[2];
  const float* ts  = (const float*)d_in[3];
  const float* Wih = (const float*)d_in[4];
  const float* Whh = (const float*)d_in[5];
  const float* bih = (const float*)d_in[6];
  const float* bhh = (const float*)d_in[7];
  const float* W1  = (const float*)d_in[8];
  const float* b1  = (const float*)d_in[9];
  const float* W2  = (const float*)d_in[10];
  const float* b2  = (const float*)d_in[11];
  float* out = (float*)d_out;

  unsigned short* wsB = (unsigned short*)d_ws;                       // 1 MB
  unsigned short* wcB = (unsigned short*)((char*)d_ws + 1048576);    // 8 KB
  float* uF = (float*)((char*)d_ws + 1048576 + 8192);                // 256 B
  unsigned short* w1B = (unsigned short*)((char*)d_ws + 1048576 + 16384);  // 32 KB
  unsigned short* w2B = (unsigned short*)((char*)d_ws + 1048576 + 49152);  // 32 KB

  prep_kernel<<<289, 256, 0, stream>>>(Wih, Whh, W1, W2, b2, wsB, wcB, uF, w1B, w2B);
  lstm_kernel<<<dim3(128, 4), 512, 0, stream>>>(x, hp, cp, wsB, bih, bhh, out);
  ode_kernel<<<1024, 64, 0, stream>>>(out, ts, wcB, uF, w1B, w2B, b1, b2);
}

// Round 18
// 77.153 us; speedup vs baseline: 1.0999x; 1.0999x over previous
//
#include <hip/hip_runtime.h>
#include <hip/hip_bf16.h>

// ODELSTMCell: B=16384, I=256, H=256, OH=64, 8 fixed dopri5 steps.
// prep_kernel : wsB=[W_ih|W_hh] bf16; Wc=W1@W2 bf16; u=b2@W1^T f32;
//               w1B=W1 bf16; w2B=W2 bf16.
// lstm_kernel : BK=32 full parity-double-buffered pipeline: BSTAGE+ALOAD for
//               kt+1 issued BEFORE compute(kt); AWRITE after; 1 barrier/iter.
// ode_kernel  : R16-measured (40.4us) zc-space zero-exchange dopri5, verbatim
//               (R17's scaled-exp2 + split-acc both reverted: regressed +7us).

#define B_N 16384
#define H_N 256

typedef __attribute__((ext_vector_type(8))) short short8;          // 8 x bf16
typedef __attribute__((ext_vector_type(4))) unsigned short u16x4;  // 4 x bf16
typedef __attribute__((ext_vector_type(4))) float f32x4;

__device__ __forceinline__ unsigned short f2bf_s(float x) {
  __hip_bfloat16 h = __float2bfloat16(x);
  return *reinterpret_cast<unsigned short*>(&h);
}

__device__ __forceinline__ short8 pack8f(const float* p) {
  const f32x4 a = *(const f32x4*)p;
  const f32x4 b = *(const f32x4*)(p + 4);
  short8 r;
  r[0] = (short)f2bf_s(a[0]); r[1] = (short)f2bf_s(a[1]);
  r[2] = (short)f2bf_s(a[2]); r[3] = (short)f2bf_s(a[3]);
  r[4] = (short)f2bf_s(b[0]); r[5] = (short)f2bf_s(b[1]);
  r[6] = (short)f2bf_s(b[2]); r[7] = (short)f2bf_s(b[3]);
  return r;
}

__device__ __forceinline__ short8 pack8v(f32x4 a, f32x4 b) {
  short8 r;
  r[0] = (short)f2bf_s(a[0]); r[1] = (short)f2bf_s(a[1]);
  r[2] = (short)f2bf_s(a[2]); r[3] = (short)f2bf_s(a[3]);
  r[4] = (short)f2bf_s(b[0]); r[5] = (short)f2bf_s(b[1]);
  r[6] = (short)f2bf_s(b[2]); r[7] = (short)f2bf_s(b[3]);
  return r;
}

__device__ __forceinline__ float fast_sigmoid(float x) {
  return __builtin_amdgcn_rcpf(1.f + __expf(-x));
}
// clamp-free: e^inf -> rcp 0 -> 1; e^-inf -> 0 -> -1  (exact limits)
__device__ __forceinline__ float fast_tanh(float x) {
  float e = __expf(2.f * x);
  return 1.f - 2.f * __builtin_amdgcn_rcpf(e + 1.f);
}

__device__ __forceinline__ void gl_lds16(const void* g, void* l) {
  __builtin_amdgcn_global_load_lds(
      (const __attribute__((address_space(1))) void*)g,
      (__attribute__((address_space(3))) void*)l, 16, 0, 0);
}

// ---------------------------------------------------------------------------
// prep: [0,256) wsB; [256,272) Wc=W1@W2; 272 u=b2@W1^T; [273,281) w1B; [281,289) w2B
// ---------------------------------------------------------------------------
__global__ __launch_bounds__(256) void prep_kernel(
    const float* __restrict__ Wih, const float* __restrict__ Whh,
    const float* __restrict__ W1, const float* __restrict__ W2,
    const float* __restrict__ b2,
    unsigned short* __restrict__ wsB, unsigned short* __restrict__ wcB,
    float* __restrict__ uF, unsigned short* __restrict__ w1B,
    unsigned short* __restrict__ w2B) {
  const int bx = blockIdx.x;
  if (bx < 256) {
    int idx = bx * 256 + threadIdx.x;
    int n = idx >> 6, c = idx & 63, k = c * 8;
    const float* src = (k < 256) ? (Wih + (size_t)n * 256 + k)
                                 : (Whh + (size_t)n * 256 + (k - 256));
    *(short8*)(wsB + (size_t)n * 512 + k) = pack8f(src);
  } else if (bx < 272) {
    int idx = (bx - 256) * 256 + threadIdx.x;  // [0,4096)
    int f = idx >> 6, o = idx & 63;
    float a0 = 0.f, a1 = 0.f, a2 = 0.f, a3 = 0.f;
    for (int h = 0; h < 256; h += 4) {
      a0 = fmaf(W1[f * 256 + h],     W2[h * 64 + o],        a0);
      a1 = fmaf(W1[f * 256 + h + 1], W2[(h + 1) * 64 + o],  a1);
      a2 = fmaf(W1[f * 256 + h + 2], W2[(h + 2) * 64 + o],  a2);
      a3 = fmaf(W1[f * 256 + h + 3], W2[(h + 3) * 64 + o],  a3);
    }
    wcB[f * 64 + o] = f2bf_s((a0 + a1) + (a2 + a3));
  } else if (bx == 272) {
    int f = threadIdx.x;
    if (f < 64) {
      float a0 = 0.f, a1 = 0.f, a2 = 0.f, a3 = 0.f;
      for (int h = 0; h < 256; h += 4) {
        a0 = fmaf(W1[f * 256 + h],     b2[h],     a0);
        a1 = fmaf(W1[f * 256 + h + 1], b2[h + 1], a1);
        a2 = fmaf(W1[f * 256 + h + 2], b2[h + 2], a2);
        a3 = fmaf(W1[f * 256 + h + 3], b2[h + 3], a3);
      }
      uF[f] = (a0 + a1) + (a2 + a3);
    }
  } else if (bx < 281) {
    int idx = (bx - 273) * 256 + threadIdx.x;  // [0,2048)
    *(short8*)(w1B + (size_t)idx * 8) = pack8f(W1 + (size_t)idx * 8);
  } else {
    int idx = (bx - 281) * 256 + threadIdx.x;  // [0,2048)
    *(short8*)(w2B + (size_t)idx * 8) = pack8f(W2 + (size_t)idx * 8);
  }
}

// ---------------------------------------------------------------------------
// lstm: grid (128, 4), 512 thr (8 waves = 2 rg x 4 cg). Block 128 x 256 cols.
// BK=32, 16 iters, parity dbuf: Abf[2][128x32] 16KB + Bbf[2][256x32] 32KB.
// iter kt (p=kt&1): BSTAGE(kt+1,p^1)+ALOAD(kt+1) -> compute(kt,p) ->
// AWRITE(p^1) -> 1 barrier. All loads issue a full compute-phase early.
// ---------------------------------------------------------------------------
__global__ __launch_bounds__(512, 4) void lstm_kernel(
    const float* __restrict__ x, const float* __restrict__ hp,
    const float* __restrict__ cp, const unsigned short* __restrict__ wsB,
    const float* __restrict__ bih, const float* __restrict__ bhh,
    float* __restrict__ out) {
  __shared__ __align__(16) unsigned short Abf[2][128 * 32];  // 8KB x2
  __shared__ __align__(16) unsigned short Bbf[2][256 * 32];  // 16KB x2

  const int tid = threadIdx.x;
  const int lane = tid & 63;
  const int wv = tid >> 6;
  const int rg = wv >> 2;
  const int cg = wv & 3;
  const int s = lane & 15, q = lane >> 4;
  const int mb = blockIdx.x * 128;
  const int hb = blockIdx.y;

  f32x4 acc[4][4];
#pragma unroll
  for (int mt = 0; mt < 4; ++mt)
#pragma unroll
    for (int g = 0; g < 4; ++g) acc[mt][g] = (f32x4){0.f, 0.f, 0.f, 0.f};

  // B staging role: wave stages chunks c16 = wv*2 + j (j=0,1)
  // row = c16*16 + (lane>>2); within-row 16B chunk = lane&3 (swizzled)
  // A staging role: row rA = tid>>2, chunk q4 = tid&3 (k = q4*8..+8)
  const int rA = tid >> 2, q4 = tid & 3;
  const int physA = q4 ^ ((rA >> 1) & 3);

  auto BSTAGE = [&](int kt, int p) {
#pragma unroll
    for (int j = 0; j < 2; ++j) {
      int c16 = wv * 2 + j;
      int row = c16 * 16 + (lane >> 2);
      int lc = (lane & 3) ^ ((row >> 1) & 3);
      int n = (row >> 6) * 256 + hb * 64 + (row & 63);
      gl_lds16(wsB + (size_t)n * 512 + kt * 32 + lc * 8,
               (char*)Bbf[p] + c16 * 1024);
    }
  };

  f32x4 pa0, pa1;
  auto ALOAD = [&](int kt) {
    const float* srcA = (kt < 8) ? x : hp;
    const int kl = (kt * 32) & 255;
    const float* ap = srcA + (size_t)(mb + rA) * 256 + kl + q4 * 8;
    pa0 = *(const f32x4*)ap;
    pa1 = *(const f32x4*)(ap + 4);
  };
  auto AWRITE = [&](int p) {
    *(short8*)((char*)Abf[p] + rA * 64 + physA * 16) = pack8v(pa0, pa1);
  };

  // prologue: stage kt=0 into buf 0
  BSTAGE(0, 0);
  ALOAD(0);
  AWRITE(0);
  __syncthreads();

  for (int kt = 0; kt < 16; ++kt) {
    const int p = kt & 1;
    if (kt < 15) {
      BSTAGE(kt + 1, p ^ 1);  // issued before compute: full-phase cover
      ALOAD(kt + 1);
    }

    // --- compute(kt, p): 16 MFMA ---
    short8 af[4];
#pragma unroll
    for (int mt = 0; mt < 4; ++mt) {
      int r = rg * 64 + mt * 16 + s;
      af[mt] = *(const short8*)((char*)Abf[p] + r * 64 +
                                ((q ^ ((r >> 1) & 3)) << 4));
    }
#pragma unroll
    for (int g = 0; g < 4; ++g) {
      int c = (g * 4 + cg) * 16 + s;
      short8 bfr = *(const short8*)((char*)Bbf[p] + c * 64 +
                                    ((q ^ ((c >> 1) & 3)) << 4));
#pragma unroll
      for (int mt = 0; mt < 4; ++mt)
        acc[mt][g] =
            __builtin_amdgcn_mfma_f32_16x16x32_bf16(af[mt], bfr, acc[mt][g], 0, 0, 0);
    }

    if (kt < 15) AWRITE(p ^ 1);
    __syncthreads();  // seals p^1 writes; WAR for BSTAGE(kt+2 -> p)
  }

  // --- fused epilogue ---
#pragma unroll
  for (int mt = 0; mt < 4; ++mt)
#pragma unroll
    for (int r = 0; r < 4; ++r) {
      int sample = mb + rg * 64 + mt * 16 + q * 4 + r;
      int h = hb * 64 + cg * 16 + s;
      float gi = acc[mt][0][r] + bih[h] + bhh[h];
      float gf = acc[mt][1][r] + bih[256 + h] + bhh[256 + h];
      float gg = acc[mt][2][r] + bih[512 + h] + bhh[512 + h];
      float go = acc[mt][3][r] + bih[768 + h] + bhh[768 + h];
      float iv = fast_sigmoid(gi), fv = fast_sigmoid(gf);
      float gv = fast_tanh(gg), ov = fast_sigmoid(go);
      float c = fv * cp[(size_t)sample * 256 + h] + iv * gv;
      float hv = ov * fast_tanh(c);
      out[(size_t)B_N * H_N + (size_t)sample * 256 + h] = c;
      out[(size_t)sample * 256 + h] = hv;
    }
}

// ---------------------------------------------------------------------------
// ode (R16-measured 40.4us, verbatim): zc-space zero-exchange per-wave
// G-space dopri5. 64 thr = 1 wave = 16 samples; feature permutation g(i,m)
// makes each thread's MFMA outputs exactly its next B-fragment.
// ---------------------------------------------------------------------------
__global__ __launch_bounds__(64) void ode_kernel(
    float* __restrict__ out, const float* __restrict__ ts,
    const unsigned short* __restrict__ wcB, const float* __restrict__ uF,
    const unsigned short* __restrict__ w1B, const unsigned short* __restrict__ w2B,
    const float* __restrict__ b1, const float* __restrict__ b2) {
  const int lane = threadIdx.x;
  const int s = lane & 15, q = lane >> 4;
  const int bb = blockIdx.x * 16;

  auto grow = [&](int i) {
    return (i >> 1) * 32 + ((s >> 2) * 8) + (i & 1) * 4 + (s & 3);
  };
  auto fbase = [&](int i) { return (i >> 1) * 32 + q * 8 + (i & 1) * 4; };

  short8 wcf[4][2];
#pragma unroll
  for (int i = 0; i < 4; ++i) {
    const int gr = grow(i);
#pragma unroll
    for (int kt = 0; kt < 2; ++kt)
      wcf[i][kt] = *(const short8*)(wcB + (size_t)gr * 64 + kt * 32 + q * 8);
  }
  f32x4 b1v[4], u4[4];
#pragma unroll
  for (int i = 0; i < 4; ++i) {
    b1v[i] = *(const f32x4*)(b1 + fbase(i));
    u4[i] = *(const f32x4*)(uF + fbase(i));
  }
  const float dt = ts[bb + s] * 0.125f;

  f32x4 G[4];
#pragma unroll
  for (int i = 0; i < 4; ++i) G[i] = (f32x4){0.f, 0.f, 0.f, 0.f};
#pragma unroll
  for (int kt = 0; kt < 8; ++kt) {
    short8 yf = pack8f(out + (size_t)(bb + s) * 256 + kt * 32 + q * 8);
#pragma unroll
    for (int i = 0; i < 4; ++i) {
      short8 w1f =
          *(const short8*)(w1B + (size_t)grow(i) * 256 + kt * 32 + q * 8);
      G[i] = __builtin_amdgcn_mfma_f32_16x16x32_bf16(w1f, yf, G[i], 0, 0, 0);
    }
  }
#pragma unroll
  for (int i = 0; i < 4; ++i) G[i] += b1v[i];  // Ghat = G + b1

  auto wcmm = [&](const f32x4 (&zc)[4], f32x4 (&o)[4]) {
    short8 zf0 = pack8v(zc[0], zc[1]);
    short8 zf1 = pack8v(zc[2], zc[3]);
#pragma unroll
    for (int i = 0; i < 4; ++i) {
      f32x4 a = (f32x4){0.f, 0.f, 0.f, 0.f};
      a = __builtin_amdgcn_mfma_f32_16x16x32_bf16(wcf[i][0], zf0, a, 0, 0, 0);
      a = __builtin_amdgcn_mfma_f32_16x16x32_bf16(wcf[i][1], zf1, a, 0, 0, 0);
      o[i] = a;
    }
  };
  auto stage = [&](const f32x4 (&zc)[4], float cj, f32x4 (&zo)[4]) {
    f32x4 o[4];
    wcmm(zc, o);
#pragma unroll
    for (int i = 0; i < 4; ++i)
#pragma unroll
      for (int r = 0; r < 4; ++r)
        zo[i][r] = fast_tanh(fmaf(dt, fmaf(cj, u4[i][r], o[i][r]), G[i][r]));
  };

  const float A31 = 3.f / 40.f, A32 = 9.f / 40.f;
  const float A41 = 44.f / 45.f, A42 = -56.f / 15.f, A43 = 32.f / 9.f;
  const float A51 = 19372.f / 6561.f, A52 = -25360.f / 2187.f,
              A53 = 64448.f / 6561.f, A54 = -212.f / 729.f;
  const float A61 = 9017.f / 3168.f, A62 = -355.f / 33.f, A63 = 46732.f / 5247.f,
              A64 = 49.f / 176.f, A65 = -5103.f / 18656.f;
  const float C1 = 35.f / 384.f, C3 = 500.f / 1113.f, C4 = 125.f / 192.f,
              C5 = -2187.f / 6784.f, C6 = 11.f / 84.f;

  f32x4 SC[4];
#pragma unroll
  for (int i = 0; i < 4; ++i) SC[i] = (f32x4){0.f, 0.f, 0.f, 0.f};
  f32x4 z1[4], z2[4], z3[4], z4[4], z5[4], zc[4];

  for (int st = 0; st < 8; ++st) {
#pragma unroll
    for (int i = 0; i < 4; ++i)
#pragma unroll
      for (int r = 0; r < 4; ++r) z1[i][r] = fast_tanh(G[i][r]);

#pragma unroll
    for (int i = 0; i < 4; ++i) zc[i] = 0.2f * z1[i];
    stage(zc, 0.2f, z2);
#pragma unroll
    for (int i = 0; i < 4; ++i) zc[i] = A31 * z1[i] + A32 * z2[i];
    stage(zc, 0.3f, z3);
#pragma unroll
    for (int i = 0; i < 4; ++i) zc[i] = A41 * z1[i] + A42 * z2[i] + A43 * z3[i];
    stage(zc, 0.8f, z4);
#pragma unroll
    for (int i = 0; i < 4; ++i)
      zc[i] = A51 * z1[i] + A52 * z2[i] + A53 * z3[i] + A54 * z4[i];
    stage(zc, 8.f / 9.f, z5);
#pragma unroll
    for (int i = 0; i < 4; ++i)
      zc[i] = A61 * z1[i] + A62 * z2[i] + A63 * z3[i] + A64 * z4[i] + A65 * z5[i];
    // stage 6 fused: z6 transient, output-combo built in place
    {
      f32x4 o[4];
      wcmm(zc, o);
#pragma unroll
      for (int i = 0; i < 4; ++i)
#pragma unroll
        for (int r = 0; r < 4; ++r) {
          float z6v = fast_tanh(fmaf(dt, u4[i][r] + o[i][r], G[i][r]));
          zc[i][r] = C1 * z1[i][r] + C3 * z3[i][r] + C4 * z4[i][r] +
                     C5 * z5[i][r] + C6 * z6v;
        }
    }
    // G += dt*(u + zC@Wc^T); SC += zC
    {
      f32x4 o6[4];
      wcmm(zc, o6);
#pragma unroll
      for (int i = 0; i < 4; ++i) {
        SC[i] += zc[i];
#pragma unroll
        for (int r = 0; r < 4; ++r)
          G[i][r] = fmaf(dt, u4[i][r] + o6[i][r], G[i][r]);
      }
    }
  }

  // epilogue: y = y0 + dt*(8*b2 + SC@W2^T)
  {
    short8 sf0 = pack8v(SC[0], SC[1]);
    short8 sf1 = pack8v(SC[2], SC[3]);
#pragma unroll
    for (int ft = 0; ft < 16; ++ft) {
      short8 w2a = *(const short8*)(w2B + (size_t)(ft * 16 + s) * 64 + q * 8);
      short8 w2b = *(const short8*)(w2B + (size_t)(ft * 16 + s) * 64 + 32 + q * 8);
      f32x4 a = (f32x4){0.f, 0.f, 0.f, 0.f};
      a = __builtin_amdgcn_mfma_f32_16x16x32_bf16(w2a, sf0, a, 0, 0, 0);
      a = __builtin_amdgcn_mfma_f32_16x16x32_bf16(w2b, sf1, a, 0, 0, 0);
      f32x4 y0 = *(const f32x4*)(out + (size_t)(bb + s) * 256 + ft * 16 + q * 4);
      f32x4 b2v = *(const f32x4*)(b2 + ft * 16 + q * 4);
#pragma unroll
      for (int r = 0; r < 4; ++r)
        y0[r] = fmaf(dt, fmaf(8.f, b2v[r], a[r]), y0[r]);
      *(f32x4*)(out + (size_t)(bb + s) * 256 + ft * 16 + q * 4) = y0;
    }
  }
}

extern "C" void kernel_launch(void* const* d_in, const int* in_sizes, int n_in,
                              void* d_out, int out_size, void* d_ws, size_t ws_size,
                              hipStream_t stream) {
  const float* x   = (const float*)d_in[0];
  const float* hp  = (const float*)d_in[1];
  const float* cp  = (const float*)d_in[2];
  const float* ts  = (const float*)d_in[3];
  const float* Wih = (const float*)d_in[4];
  const float* Whh = (const float*)d_in[5];
  const float* bih = (const float*)d_in[6];
  const float* bhh = (const float*)d_in[7];
  const float* W1  = (const float*)d_in[8];
  const float* b1  = (const float*)d_in[9];
  const float* W2  = (const float*)d_in[10];
  const float* b2  = (const float*)d_in[11];
  float* out = (float*)d_out;

  unsigned short* wsB = (unsigned short*)d_ws;                       // 1 MB
  unsigned short* wcB = (unsigned short*)((char*)d_ws + 1048576);    // 8 KB
  float* uF = (float*)((char*)d_ws + 1048576 + 8192);                // 256 B
  unsigned short* w1B = (unsigned short*)((char*)d_ws + 1048576 + 16384);  // 32 KB
  unsigned short* w2B = (unsigned short*)((char*)d_ws + 1048576 + 49152);  // 32 KB

  prep_kernel<<<289, 256, 0, stream>>>(Wih, Whh, W1, W2, b2, wsB, wcB, uF, w1B, w2B);
  lstm_kernel<<<dim3(128, 4), 512, 0, stream>>>(x, hp, cp, wsB, bih, bhh, out);
  ode_kernel<<<1024, 64, 0, stream>>>(out, ts, wcB, uF, w1B, w2B, b1, b2);
}